// Round 10
// baseline (667.398 us; speedup 1.0000x reference)
//
#include <hip/hip_runtime.h>
#include <math.h>

#define N_NODES 50000
#define N_EDGES 500000
#define NPB 16      // nodes per conv block (50000 = 16 * 3125)
#define GROUPS 8    // 32-lane groups per 256-thread block

typedef __attribute__((ext_vector_type(8))) short bf16x8;
typedef __attribute__((ext_vector_type(16))) float f32x16;

__device__ __forceinline__ float gelu_fast(float x) {
    const float k0 = 0.7978845608028654f;
    const float k1 = 0.044715f;
    float z2 = 2.f * k0 * (x + k1 * x * x * x);
    float ez = __expf(z2);
    float th = 1.f - 2.f * __builtin_amdgcn_rcpf(ez + 1.f);
    return 0.5f * x * (1.f + th);
}

__device__ __forceinline__ unsigned short f2bf(float x) {
    unsigned int u = __float_as_uint(x);
    unsigned int r = (u + 0x7FFFu + ((u >> 16) & 1u)) >> 16;  // RNE
    return (unsigned short)r;
}
__device__ __forceinline__ unsigned int pack2bf(float a, float b) {
    return (unsigned int)f2bf(a) | ((unsigned int)f2bf(b) << 16);
}
__device__ __forceinline__ float bf2f(unsigned short b) {
    return __uint_as_float(((unsigned int)b) << 16);
}

__device__ __forceinline__ void lds_add(float* p, float v) {
    unsigned int off = (unsigned int)(size_t)p;
    asm volatile("ds_add_f32 %0, %1" :: "v"(off), "v"(v) : "memory");
}

__device__ __forceinline__ bf16x8 mk_frag4(unsigned int w0, unsigned int w1,
                                           unsigned int w2, unsigned int w3) {
    union { unsigned int u[4]; bf16x8 v; } x;
    x.u[0] = w0; x.u[1] = w1; x.u[2] = w2; x.u[3] = w3;
    return x.v;
}

// K1: per-node lift.
__global__ void node_pre(const float* __restrict__ node_input,
                         const float* __restrict__ W1_s,
                         const float* __restrict__ W1_v,
                         float* __restrict__ feat,
                         float* __restrict__ out) {
    __shared__ float lWs[32 * 64];
    __shared__ float lWv[32 * 64];
    for (int i = threadIdx.x; i < 2048; i += blockDim.x) {
        lWs[i] = W1_s[i];
        lWv[i] = W1_v[i];
    }
    __syncthreads();
    int n = blockIdx.x * blockDim.x + threadIdx.x;
    if (n >= N_NODES) return;
    const float inv_sqrt_mul = 0.17677669529663687f;
    const float a_mix = 0.9219544457292887f;

    float s[32];
#pragma unroll
    for (int u = 0; u < 32; ++u) s[u] = node_input[n * 128 + u];
#pragma unroll 4
    for (int w = 0; w < 64; ++w) {
        float acc = 0.f;
#pragma unroll
        for (int u = 0; u < 32; ++u) acc += s[u] * lWs[u * 64 + w];
        acc *= inv_sqrt_mul;
        if (w < 32) feat[(size_t)n * 128 + w * 4 + 0] = acc;
        else        out[n * 128 + (w - 32)] = a_mix * acc;
    }
#pragma unroll
    for (int k = 0; k < 3; ++k) {
        float vk[32];
#pragma unroll
        for (int u = 0; u < 32; ++u) vk[u] = node_input[n * 128 + 32 + u * 3 + k];
#pragma unroll 4
        for (int w = 0; w < 64; ++w) {
            float acc = 0.f;
#pragma unroll
            for (int u = 0; u < 32; ++u) acc += vk[u] * lWv[u * 64 + w];
            acc *= inv_sqrt_mul;
            if (w < 32) feat[(size_t)n * 128 + w * 4 + 1 + k] = acc;
            else        out[n * 128 + 32 + (w - 32) * 3 + k] = a_mix * acc;
        }
    }
}

// K2a
__global__ void hist_kernel(const int* __restrict__ edge_dst, int* __restrict__ counts) {
    int e = blockIdx.x * blockDim.x + threadIdx.x;
    if (e < N_EDGES) atomicAdd(&counts[edge_dst[e]], 1);
}

// K2b
__global__ void scan_kernel(const int* __restrict__ counts,
                            int* __restrict__ offsets,
                            int* __restrict__ cursor) {
    const int T = 1024;
    __shared__ int partial[T];
    int t = threadIdx.x;
    const int chunk = (N_NODES + T - 1) / T;
    int start = t * chunk;
    int end = start + chunk; if (end > N_NODES) end = N_NODES;
    if (start > N_NODES) start = N_NODES;
    int sum = 0;
    for (int i = start; i < end; ++i) sum += counts[i];
    partial[t] = sum;
    __syncthreads();
    for (int off = 1; off < T; off <<= 1) {
        int other = (t >= off) ? partial[t - off] : 0;
        __syncthreads();
        partial[t] += other;
        __syncthreads();
    }
    int run = (t == 0) ? 0 : partial[t - 1];
    for (int i = start; i < end; ++i) {
        offsets[i] = run;
        cursor[i] = run;
        run += counts[i];
    }
    if (t == T - 1) offsets[N_NODES] = run;
}

// K2c
__global__ void scatter_kernel(const int* __restrict__ edge_src,
                               const int* __restrict__ edge_dst,
                               const float* __restrict__ edge_attr,
                               int* __restrict__ cursor,
                               float4* __restrict__ ySorted,
                               int4* __restrict__ sde) {
    int e = blockIdx.x * blockDim.x + threadIdx.x;
    if (e >= N_EDGES) return;
    int d = edge_dst[e];
    int pos = atomicAdd(&cursor[d], 1);
    ySorted[pos] = *(const float4*)(edge_attr + (size_t)e * 4);
    sde[pos] = make_int4(edge_src[e], d, e, 0);
}

// K_mlp: MFMA batched-GEMM edge MLP in swapped form (edge = column).
// Per wave-batch of 32 edges: L1 = 1 MFMA (K 8->16 zero-pad), L2 = 2, L3 = 8.
// Weights live in per-lane VGPR fragments loaded once per wave.
// C/D layout (verified): col=lane&31, row=(reg&3)+8*(reg>>2)+4*(lane>>5).
// A/B layout (CDNA convention): row/col=lane&31, k=(lane>>5)*8+i.
__global__ void __launch_bounds__(256)
mlp_kernel(const float* __restrict__ edge_scalars,
           const float* __restrict__ M0,
           const float* __restrict__ M1,
           const float* __restrict__ Wtp0,
           const float* __restrict__ Wtp1,
           const float* __restrict__ Wtp2,
           const float* __restrict__ Wtp3,
           uint4* __restrict__ wOut16) {
    __shared__ unsigned int smem[4 * 68 * 32];  // per-wave 68-dword rows x 32 edges

    const int wv   = threadIdx.x >> 6;
    const int lane = threadIdx.x & 63;
    const int col  = lane & 31;
    const int a    = lane >> 5;
    unsigned int* wsm = smem + wv * (68 * 32);

    const float inv_sqrt8  = 0.35355339059327373f;
    const float inv_sqrt32 = 0.17677669529663687f;

    // ---- one-time weight fragments ----
    bf16x8 A1, A2[2], A3[4][2];
    {
        union { short h[8]; bf16x8 v; } x;
#pragma unroll
        for (int i = 0; i < 8; ++i)
            x.h[i] = (a == 0) ? (short)f2bf(M0[i * 32 + col]) : (short)0;
        A1 = x.v;
#pragma unroll
        for (int ks = 0; ks < 2; ++ks) {
            union { short h[8]; bf16x8 v; } y;
#pragma unroll
            for (int i = 0; i < 8; ++i)
                y.h[i] = (short)f2bf(M1[(ks * 16 + a * 8 + i) * 32 + col]);
            A2[ks] = y.v;
        }
        const float* Wsel = (lane & 3) == 0 ? Wtp0 :
                            (lane & 3) == 1 ? Wtp1 :
                            (lane & 3) == 2 ? Wtp2 : Wtp3;
        const int colw0 = (col >> 2);
#pragma unroll
        for (int t = 0; t < 4; ++t) {
#pragma unroll
            for (int ks = 0; ks < 2; ++ks) {
                union { short h[8]; bf16x8 v; } y;
#pragma unroll
                for (int i = 0; i < 8; ++i)
                    y.h[i] = (short)f2bf(Wsel[(ks * 16 + a * 8 + i) * 32 + t * 8 + colw0]);
                A3[t][ks] = y.v;
            }
        }
    }

    const int wave_id = blockIdx.x * 4 + wv;
    const int n_waves = gridDim.x * 4;
    const int NB = N_EDGES / 32;  // 15625 exact

    for (int b = wave_id; b < NB; b += n_waves) {
        const int e0 = b * 32;

        // ---- B1: edge scalars (K=8, zero-padded to 16) ----
        bf16x8 B1;
        {
            union { short h[8]; bf16x8 v; } x;
            if (a == 0) {
                const float4 s0 = *(const float4*)(edge_scalars + (size_t)(e0 + col) * 8);
                const float4 s1 = *(const float4*)(edge_scalars + (size_t)(e0 + col) * 8 + 4);
                x.h[0] = (short)f2bf(s0.x); x.h[1] = (short)f2bf(s0.y);
                x.h[2] = (short)f2bf(s0.z); x.h[3] = (short)f2bf(s0.w);
                x.h[4] = (short)f2bf(s1.x); x.h[5] = (short)f2bf(s1.y);
                x.h[6] = (short)f2bf(s1.z); x.h[7] = (short)f2bf(s1.w);
            } else {
#pragma unroll
                for (int i = 0; i < 8; ++i) x.h[i] = 0;
            }
            B1 = x.v;
        }

        // ---- layer 1 ----
        f32x16 d1;
#pragma unroll
        for (int r = 0; r < 16; ++r) d1[r] = 0.f;
        d1 = __builtin_amdgcn_mfma_f32_32x32x16_bf16(A1, B1, d1, 0, 0, 0);

        float g1[16];
#pragma unroll
        for (int r = 0; r < 16; ++r) g1[r] = gelu_fast(d1[r] * inv_sqrt8);

        // ---- transition: C-layout -> B-frags (own + partner half) ----
        bf16x8 B2[2];
        {
            unsigned int p01 = pack2bf(g1[0], g1[1]),   p23 = pack2bf(g1[2], g1[3]);
            unsigned int p45 = pack2bf(g1[4], g1[5]),   p67 = pack2bf(g1[6], g1[7]);
            unsigned int p89 = pack2bf(g1[8], g1[9]),   pAB = pack2bf(g1[10], g1[11]);
            unsigned int pCD = pack2bf(g1[12], g1[13]), pEF = pack2bf(g1[14], g1[15]);
            unsigned int q01 = __shfl_xor(p01, 32, 64), q23 = __shfl_xor(p23, 32, 64);
            unsigned int q45 = __shfl_xor(p45, 32, 64), q67 = __shfl_xor(p67, 32, 64);
            unsigned int q89 = __shfl_xor(p89, 32, 64), qAB = __shfl_xor(pAB, 32, 64);
            unsigned int qCD = __shfl_xor(pCD, 32, 64), qEF = __shfl_xor(pEF, 32, 64);
            B2[0] = a ? mk_frag4(q45, q67, p45, p67) : mk_frag4(p01, p23, q01, q23);
            B2[1] = a ? mk_frag4(qCD, qEF, pCD, pEF) : mk_frag4(p89, pAB, q89, qAB);
        }

        // ---- layer 2 ----
        f32x16 d2;
#pragma unroll
        for (int r = 0; r < 16; ++r) d2[r] = 0.f;
        d2 = __builtin_amdgcn_mfma_f32_32x32x16_bf16(A2[0], B2[0], d2, 0, 0, 0);
        d2 = __builtin_amdgcn_mfma_f32_32x32x16_bf16(A2[1], B2[1], d2, 0, 0, 0);

        float g2[16];
#pragma unroll
        for (int r = 0; r < 16; ++r) g2[r] = gelu_fast(d2[r] * inv_sqrt32);

        bf16x8 B3[2];
        {
            unsigned int p01 = pack2bf(g2[0], g2[1]),   p23 = pack2bf(g2[2], g2[3]);
            unsigned int p45 = pack2bf(g2[4], g2[5]),   p67 = pack2bf(g2[6], g2[7]);
            unsigned int p89 = pack2bf(g2[8], g2[9]),   pAB = pack2bf(g2[10], g2[11]);
            unsigned int pCD = pack2bf(g2[12], g2[13]), pEF = pack2bf(g2[14], g2[15]);
            unsigned int q01 = __shfl_xor(p01, 32, 64), q23 = __shfl_xor(p23, 32, 64);
            unsigned int q45 = __shfl_xor(p45, 32, 64), q67 = __shfl_xor(p67, 32, 64);
            unsigned int q89 = __shfl_xor(p89, 32, 64), qAB = __shfl_xor(pAB, 32, 64);
            unsigned int qCD = __shfl_xor(pCD, 32, 64), qEF = __shfl_xor(pEF, 32, 64);
            B3[0] = a ? mk_frag4(q45, q67, p45, p67) : mk_frag4(p01, p23, q01, q23);
            B3[1] = a ? mk_frag4(qCD, qEF, pCD, pEF) : mk_frag4(p89, pAB, q89, qAB);
        }

        // ---- layer 3: 4 output tiles of 32 channels; epilogue per tile ----
#pragma unroll 1
        for (int t = 0; t < 4; ++t) {
            f32x16 d3;
#pragma unroll
            for (int r = 0; r < 16; ++r) d3[r] = 0.f;
            d3 = __builtin_amdgcn_mfma_f32_32x32x16_bf16(A3[t][0], B3[0], d3, 0, 0, 0);
            d3 = __builtin_amdgcn_mfma_f32_32x32x16_bf16(A3[t][1], B3[1], d3, 0, 0, 0);
#pragma unroll
            for (int q = 0; q < 4; ++q) {
                unsigned int w0 = pack2bf(d3[4 * q + 0] * inv_sqrt32,
                                          d3[4 * q + 1] * inv_sqrt32);
                unsigned int w1 = pack2bf(d3[4 * q + 2] * inv_sqrt32,
                                          d3[4 * q + 3] * inv_sqrt32);
                const int dw = col * 68 + (t * 16 + 4 * q + 2 * a);
                uint2 pk; pk.x = w0; pk.y = w1;
                *(uint2*)&wsm[dw] = pk;
            }
        }
        asm volatile("s_waitcnt lgkmcnt(0)" ::: "memory");

        // coalesced copy-out: 32 edges x 256B
#pragma unroll
        for (int it = 0; it < 8; ++it) {
            const int e = it * 4 + (lane >> 4);
            const int c = lane & 15;
            const uint4 v = *(const uint4*)&wsm[e * 68 + c * 4];
            wOut16[(size_t)(e0 + e) * 16 + c] = v;
        }
        asm volatile("s_waitcnt lgkmcnt(0)" ::: "memory");
    }
}

// K_conv: unchanged.
__global__ void __launch_bounds__(256)
conv_kernel(const ushort4* __restrict__ wOut,
            const float4* __restrict__ ySorted,
            const int4* __restrict__ sde,
            const int* __restrict__ offsets,
            const float* __restrict__ W2_s,
            const float* __restrict__ W2_v,
            const float* __restrict__ feat,
            float* __restrict__ out) {
    __shared__ float sacc[NPB * 256];
    for (int i = threadIdx.x; i < NPB * 256; i += blockDim.x) sacc[i] = 0.f;
    __syncthreads();

    const int lane = threadIdx.x & 31;
    const int g = threadIdx.x >> 5;
    const int n0 = blockIdx.x * NPB;
    const int eb = offsets[n0];
    const int ee = offsets[n0 + NPB];
    const float INV3 = 0.5773502691896258f;
    const float4* feat4 = (const float4*)feat;

    const int total = ee - eb;
    const int per = (total + GROUPS - 1) / GROUPS;
    const int es = eb + g * per;
    int et = es + per; if (et > ee) et = ee;

    float r0 = 0.f, r1 = 0.f, r2 = 0.f, r3 = 0.f;
    float r4 = 0.f, r5 = 0.f, r6 = 0.f, r7 = 0.f;
    int cur = -1;

#pragma unroll 2
    for (int e = es; e < et; ++e) {
        const int4 sd = sde[e];
        const ushort4 wq = wOut[(size_t)sd.z * 32 + lane];
        const float4 yq = ySorted[e];
        const float4 f = feat4[(size_t)sd.x * 32 + lane];

        if (sd.y != cur) {
            if (cur >= 0) {
                float* ap = sacc + (cur - n0) * 256;
                lds_add(ap + lane, r0);
                lds_add(ap + 32 + lane, r1);
                lds_add(ap + 64 + lane * 3 + 0, r2);
                lds_add(ap + 64 + lane * 3 + 1, r3);
                lds_add(ap + 64 + lane * 3 + 2, r4);
                lds_add(ap + 160 + lane * 3 + 0, r5);
                lds_add(ap + 160 + lane * 3 + 1, r6);
                lds_add(ap + 160 + lane * 3 + 2, r7);
            }
            cur = sd.y;
            r0 = r1 = r2 = r3 = r4 = r5 = r6 = r7 = 0.f;
        }

        const float w0 = bf2f(wq.x), w1 = bf2f(wq.y);
        const float w2 = bf2f(wq.z), w3 = bf2f(wq.w);
        const float dvy = f.y * yq.y + f.z * yq.z + f.w * yq.w;
        const float w1es = w1 * f.x;
        const float w2y0 = w2 * yq.x;

        r0 += w0 * f.x * yq.x;
        r1 += w3 * dvy * INV3;
        r2 += w1es * yq.y;
        r3 += w1es * yq.z;
        r4 += w1es * yq.w;
        r5 += w2y0 * f.y;
        r6 += w2y0 * f.z;
        r7 += w2y0 * f.w;
    }
    if (cur >= 0) {
        float* ap = sacc + (cur - n0) * 256;
        lds_add(ap + lane, r0);
        lds_add(ap + 32 + lane, r1);
        lds_add(ap + 64 + lane * 3 + 0, r2);
        lds_add(ap + 64 + lane * 3 + 1, r3);
        lds_add(ap + 64 + lane * 3 + 2, r4);
        lds_add(ap + 160 + lane * 3 + 0, r5);
        lds_add(ap + 160 + lane * 3 + 1, r6);
        lds_add(ap + 160 + lane * 3 + 2, r7);
    }
    asm volatile("s_waitcnt lgkmcnt(0)" ::: "memory");
    __syncthreads();

    const float scale = 0.31622776601683794f * 0.125f * 0.3872983346207417f;
    for (int li = g; li < NPB; li += GROUPS) {
        const float* ap = sacc + li * 256;
        float cs = 0.f, cv0 = 0.f, cv1 = 0.f, cv2 = 0.f;
#pragma unroll 8
        for (int j = 0; j < 64; ++j) {
            const float as = ap[j];
            cs += as * __ldg(&W2_s[j * 32 + lane]);
            const float wv = __ldg(&W2_v[j * 32 + lane]);
            cv0 += ap[64 + 3 * j + 0] * wv;
            cv1 += ap[64 + 3 * j + 1] * wv;
            cv2 += ap[64 + 3 * j + 2] * wv;
        }
        float* o = out + (size_t)(n0 + li) * 128;
        o[lane]              += scale * cs;
        o[32 + lane * 3 + 0] += scale * cv0;
        o[32 + lane * 3 + 1] += scale * cv1;
        o[32 + lane * 3 + 2] += scale * cv2;
    }
}

extern "C" void kernel_launch(void* const* d_in, const int* in_sizes, int n_in,
                              void* d_out, int out_size, void* d_ws, size_t ws_size,
                              hipStream_t stream) {
    const float* node_input   = (const float*)d_in[0];
    const float* edge_attr    = (const float*)d_in[1];
    const float* edge_scalars = (const float*)d_in[2];
    const float* W1_s = (const float*)d_in[3];
    const float* W1_v = (const float*)d_in[4];
    const float* M0   = (const float*)d_in[5];
    const float* M1   = (const float*)d_in[6];
    const float* Wtp0 = (const float*)d_in[7];
    const float* Wtp1 = (const float*)d_in[8];
    const float* Wtp2 = (const float*)d_in[9];
    const float* Wtp3 = (const float*)d_in[10];
    const float* W2_s = (const float*)d_in[11];
    const float* W2_v = (const float*)d_in[12];
    const int* edge_src = (const int*)d_in[13];
    const int* edge_dst = (const int*)d_in[14];
    float* out = (float*)d_out;
    float* ws  = (float*)d_ws;

    float*  feat    = ws;                                           // N*128 (25.6 MB)
    float4* ySorted = (float4*)(feat + (size_t)N_NODES * 128);      // E float4 (8 MB)
    ushort4* wOut   = (ushort4*)(ySorted + N_EDGES);                // E*32 ushort4 (128 MB)
    int4*  sde      = (int4*)(wOut + (size_t)N_EDGES * 32);         // E int4 (8 MB)
    int*   counts   = (int*)(sde + N_EDGES);                        // N
    int*   offsets  = counts + N_NODES;                             // N+1
    int*   cursor   = offsets + N_NODES + 1;                        // N

    hipMemsetAsync(counts, 0, N_NODES * sizeof(int), stream);

    node_pre<<<(N_NODES + 255) / 256, 256, 0, stream>>>(node_input, W1_s, W1_v,
                                                        feat, out);

    hist_kernel<<<(N_EDGES + 255) / 256, 256, 0, stream>>>(edge_dst, counts);
    scan_kernel<<<1, 1024, 0, stream>>>(counts, offsets, cursor);
    scatter_kernel<<<(N_EDGES + 255) / 256, 256, 0, stream>>>(edge_src, edge_dst,
                                                              edge_attr,
                                                              cursor, ySorted, sde);

    mlp_kernel<<<512, 256, 0, stream>>>(edge_scalars, M0, M1,
                                        Wtp0, Wtp1, Wtp2, Wtp3,
                                        (uint4*)wOut);

    conv_kernel<<<N_NODES / NPB, 256, 0, stream>>>(wOut, ySorted, sde, offsets,
                                                   W2_s, W2_v, feat, out);
}

// Round 11
// 561.912 us; speedup vs baseline: 1.1877x; 1.1877x over previous
//
#include <hip/hip_runtime.h>
#include <math.h>

#define N_NODES 50000
#define N_EDGES 500000
#define NPB 16      // nodes per conv block (50000 = 16 * 3125)
#define GROUPS 8    // 32-lane groups per 256-thread block

__device__ __forceinline__ float gelu_fast(float x) {
    const float k0 = 0.7978845608028654f;
    const float k1 = 0.044715f;
    float z2 = 2.f * k0 * (x + k1 * x * x * x);
    float ez = __expf(z2);
    float th = 1.f - 2.f * __builtin_amdgcn_rcpf(ez + 1.f);
    return 0.5f * x * (1.f + th);
}

__device__ __forceinline__ unsigned short f2bf(float x) {
    unsigned int u = __float_as_uint(x);
    unsigned int r = (u + 0x7FFFu + ((u >> 16) & 1u)) >> 16;  // RNE
    return (unsigned short)r;
}
__device__ __forceinline__ unsigned int pack2bf(float a, float b) {
    return (unsigned int)f2bf(a) | ((unsigned int)f2bf(b) << 16);
}
__device__ __forceinline__ float bf_lo(unsigned int w) {
    return __uint_as_float(w << 16);
}
__device__ __forceinline__ float bf_hi(unsigned int w) {
    return __uint_as_float(w & 0xffff0000u);
}

__device__ __forceinline__ void lds_add(float* p, float v) {
    unsigned int off = (unsigned int)(size_t)p;
    asm volatile("ds_add_f32 %0, %1" :: "v"(off), "v"(v) : "memory");
}

// K1: per-node lift.
__global__ void node_pre(const float* __restrict__ node_input,
                         const float* __restrict__ W1_s,
                         const float* __restrict__ W1_v,
                         float* __restrict__ feat,
                         float* __restrict__ out) {
    __shared__ float lWs[32 * 64];
    __shared__ float lWv[32 * 64];
    for (int i = threadIdx.x; i < 2048; i += blockDim.x) {
        lWs[i] = W1_s[i];
        lWv[i] = W1_v[i];
    }
    __syncthreads();
    int n = blockIdx.x * blockDim.x + threadIdx.x;
    if (n >= N_NODES) return;
    const float inv_sqrt_mul = 0.17677669529663687f;
    const float a_mix = 0.9219544457292887f;

    float s[32];
#pragma unroll
    for (int u = 0; u < 32; ++u) s[u] = node_input[n * 128 + u];
#pragma unroll 4
    for (int w = 0; w < 64; ++w) {
        float acc = 0.f;
#pragma unroll
        for (int u = 0; u < 32; ++u) acc += s[u] * lWs[u * 64 + w];
        acc *= inv_sqrt_mul;
        if (w < 32) feat[(size_t)n * 128 + w * 4 + 0] = acc;
        else        out[n * 128 + (w - 32)] = a_mix * acc;
    }
#pragma unroll
    for (int k = 0; k < 3; ++k) {
        float vk[32];
#pragma unroll
        for (int u = 0; u < 32; ++u) vk[u] = node_input[n * 128 + 32 + u * 3 + k];
#pragma unroll 4
        for (int w = 0; w < 64; ++w) {
            float acc = 0.f;
#pragma unroll
            for (int u = 0; u < 32; ++u) acc += vk[u] * lWv[u * 64 + w];
            acc *= inv_sqrt_mul;
            if (w < 32) feat[(size_t)n * 128 + w * 4 + 1 + k] = acc;
            else        out[n * 128 + 32 + (w - 32) * 3 + k] = a_mix * acc;
        }
    }
}

// K2a
__global__ void hist_kernel(const int* __restrict__ edge_dst, int* __restrict__ counts) {
    int e = blockIdx.x * blockDim.x + threadIdx.x;
    if (e < N_EDGES) atomicAdd(&counts[edge_dst[e]], 1);
}

// K2b
__global__ void scan_kernel(const int* __restrict__ counts,
                            int* __restrict__ offsets,
                            int* __restrict__ cursor) {
    const int T = 1024;
    __shared__ int partial[T];
    int t = threadIdx.x;
    const int chunk = (N_NODES + T - 1) / T;
    int start = t * chunk;
    int end = start + chunk; if (end > N_NODES) end = N_NODES;
    if (start > N_NODES) start = N_NODES;
    int sum = 0;
    for (int i = start; i < end; ++i) sum += counts[i];
    partial[t] = sum;
    __syncthreads();
    for (int off = 1; off < T; off <<= 1) {
        int other = (t >= off) ? partial[t - off] : 0;
        __syncthreads();
        partial[t] += other;
        __syncthreads();
    }
    int run = (t == 0) ? 0 : partial[t - 1];
    for (int i = start; i < end; ++i) {
        offsets[i] = run;
        cursor[i] = run;
        run += counts[i];
    }
    if (t == T - 1) offsets[N_NODES] = run;
}

// K2c
__global__ void scatter_kernel(const int* __restrict__ edge_src,
                               const int* __restrict__ edge_dst,
                               const float* __restrict__ edge_attr,
                               int* __restrict__ cursor,
                               float4* __restrict__ ySorted,
                               int4* __restrict__ sde) {
    int e = blockIdx.x * blockDim.x + threadIdx.x;
    if (e >= N_EDGES) return;
    int d = edge_dst[e];
    int pos = atomicAdd(&cursor[d], 1);
    ySorted[pos] = *(const float4*)(edge_attr + (size_t)e * 4);
    sde[pos] = make_int4(edge_src[e], d, e, 0);
}

// K_h: layers 1+2 only. One thread per input-order edge; SGPR weights;
// h written as 32 bf16 (64B/edge) via wave-private LDS transpose.
__global__ void __launch_bounds__(256)
h_kernel(const float* __restrict__ edge_scalars,
         const float* __restrict__ M0,
         const float* __restrict__ M1,
         uint4* __restrict__ hOut) {
    __shared__ unsigned int stage[256 * 20];  // 20 dwords/row: 16 data + 4 pad

    const int wv   = threadIdx.x >> 6;
    const int lane = threadIdx.x & 63;
    const int e0w  = blockIdx.x * 256 + wv * 64;
    int e = e0w + lane;
    int ec = e < N_EDGES ? e : N_EDGES - 1;

    const float inv_sqrt8  = 0.35355339059327373f;
    const float inv_sqrt32 = 0.17677669529663687f;

    const float4 s0 = *(const float4*)(edge_scalars + (size_t)ec * 8);
    const float4 s1 = *(const float4*)(edge_scalars + (size_t)ec * 8 + 4);

    // layer 1
    float t[32];
#pragma unroll
    for (int u = 0; u < 32; ++u) {
        float acc = s0.x * M0[0 * 32 + u] + s0.y * M0[1 * 32 + u]
                  + s0.z * M0[2 * 32 + u] + s0.w * M0[3 * 32 + u]
                  + s1.x * M0[4 * 32 + u] + s1.y * M0[5 * 32 + u]
                  + s1.z * M0[6 * 32 + u] + s1.w * M0[7 * 32 + u];
        t[u] = gelu_fast(acc * inv_sqrt8);
    }
    // layer 2
    float h[32];
#pragma unroll
    for (int u = 0; u < 32; ++u) {
        float acc = 0.f;
#pragma unroll
        for (int m = 0; m < 32; ++m) acc += t[m] * M1[m * 32 + u];
        h[u] = gelu_fast(acc * inv_sqrt32);
    }

    // pack 32 bf16 -> 16 dwords, stage, coalesced copy-out
    unsigned int* myrow = stage + threadIdx.x * 20;
#pragma unroll
    for (int c = 0; c < 4; ++c) {
        uint4 pk;
        pk.x = pack2bf(h[c * 8 + 0], h[c * 8 + 1]);
        pk.y = pack2bf(h[c * 8 + 2], h[c * 8 + 3]);
        pk.z = pack2bf(h[c * 8 + 4], h[c * 8 + 5]);
        pk.w = pack2bf(h[c * 8 + 6], h[c * 8 + 7]);
        *(uint4*)&myrow[c * 4] = pk;
    }
    asm volatile("s_waitcnt lgkmcnt(0)" ::: "memory");
#pragma unroll
    for (int p = 0; p < 4; ++p) {
        const int el = p * 16 + (lane >> 2);
        const int c  = lane & 3;
        const uint4 v = *(const uint4*)&stage[(wv * 64 + el) * 20 + c * 4];
        const int ge = e0w + el;
        if (ge < N_EDGES)
            hOut[(size_t)ge * 4 + c] = v;
    }
}

// K_conv: block owns NPB contiguous dst nodes. Per edge: h (uniform, 4
// broadcast uint4 loads) x per-lane Wtp column (packed bf16 VGPRs, 1/sqrt32
// pre-folded) -> w0..w3; message; register run-combining; ds_add_f32.
__global__ void __launch_bounds__(256)
conv_kernel(const uint4* __restrict__ hBuf,
            const float4* __restrict__ ySorted,
            const int4* __restrict__ sde,
            const int* __restrict__ offsets,
            const float* __restrict__ Wtp0,
            const float* __restrict__ Wtp1,
            const float* __restrict__ Wtp2,
            const float* __restrict__ Wtp3,
            const float* __restrict__ W2_s,
            const float* __restrict__ W2_v,
            const float* __restrict__ feat,
            float* __restrict__ out) {
    __shared__ float sacc[NPB * 256];
    for (int i = threadIdx.x; i < NPB * 256; i += blockDim.x) sacc[i] = 0.f;

    const int lane = threadIdx.x & 31;
    const int g = threadIdx.x >> 5;

    // one-time per-lane Wtp columns (channel = lane), 1/sqrt(32) folded in
    const float inv_sqrt32 = 0.17677669529663687f;
    unsigned int wA[32], wB[32];
#pragma unroll
    for (int j = 0; j < 32; ++j) {
        wA[j] = pack2bf(Wtp0[j * 32 + lane] * inv_sqrt32,
                        Wtp1[j * 32 + lane] * inv_sqrt32);
        wB[j] = pack2bf(Wtp2[j * 32 + lane] * inv_sqrt32,
                        Wtp3[j * 32 + lane] * inv_sqrt32);
    }
    __syncthreads();

    const int n0 = blockIdx.x * NPB;
    const int eb = offsets[n0];
    const int ee = offsets[n0 + NPB];
    const float INV3 = 0.5773502691896258f;
    const float4* feat4 = (const float4*)feat;

    const int total = ee - eb;
    const int per = (total + GROUPS - 1) / GROUPS;
    const int es = eb + g * per;
    int et = es + per; if (et > ee) et = ee;

    float r0 = 0.f, r1 = 0.f, r2 = 0.f, r3 = 0.f;
    float r4 = 0.f, r5 = 0.f, r6 = 0.f, r7 = 0.f;
    int cur = -1;

    for (int e = es; e < et; ++e) {
        const int4 sd = sde[e];
        const float4 yq = ySorted[e];                    // uniform per group
        const float4 f = feat4[(size_t)sd.x * 32 + lane];
        const uint4 hq0 = hBuf[(size_t)sd.z * 4 + 0];    // uniform per group
        const uint4 hq1 = hBuf[(size_t)sd.z * 4 + 1];
        const uint4 hq2 = hBuf[(size_t)sd.z * 4 + 2];
        const uint4 hq3 = hBuf[(size_t)sd.z * 4 + 3];

        if (sd.y != cur) {
            if (cur >= 0) {
                float* ap = sacc + (cur - n0) * 256;
                lds_add(ap + lane, r0);
                lds_add(ap + 32 + lane, r1);
                lds_add(ap + 64 + lane * 3 + 0, r2);
                lds_add(ap + 64 + lane * 3 + 1, r3);
                lds_add(ap + 64 + lane * 3 + 2, r4);
                lds_add(ap + 160 + lane * 3 + 0, r5);
                lds_add(ap + 160 + lane * 3 + 1, r6);
                lds_add(ap + 160 + lane * 3 + 2, r7);
            }
            cur = sd.y;
            r0 = r1 = r2 = r3 = r4 = r5 = r6 = r7 = 0.f;
        }

        // layer 3 for this lane's channel u=lane
        float w0 = 0.f, w1 = 0.f, w2 = 0.f, w3 = 0.f;
        unsigned int hw[16] = {hq0.x, hq0.y, hq0.z, hq0.w,
                               hq1.x, hq1.y, hq1.z, hq1.w,
                               hq2.x, hq2.y, hq2.z, hq2.w,
                               hq3.x, hq3.y, hq3.z, hq3.w};
#pragma unroll
        for (int k = 0; k < 16; ++k) {
            const float hlo = bf_lo(hw[k]);
            const float hhi = bf_hi(hw[k]);
            const unsigned int a0 = wA[2 * k],     b0 = wB[2 * k];
            const unsigned int a1 = wA[2 * k + 1], b1 = wB[2 * k + 1];
            w0 += hlo * bf_lo(a0); w1 += hlo * bf_hi(a0);
            w2 += hlo * bf_lo(b0); w3 += hlo * bf_hi(b0);
            w0 += hhi * bf_lo(a1); w1 += hhi * bf_hi(a1);
            w2 += hhi * bf_lo(b1); w3 += hhi * bf_hi(b1);
        }

        const float dvy = f.y * yq.y + f.z * yq.z + f.w * yq.w;
        const float w1es = w1 * f.x;
        const float w2y0 = w2 * yq.x;

        r0 += w0 * f.x * yq.x;
        r1 += w3 * dvy * INV3;
        r2 += w1es * yq.y;
        r3 += w1es * yq.z;
        r4 += w1es * yq.w;
        r5 += w2y0 * f.y;
        r6 += w2y0 * f.z;
        r7 += w2y0 * f.w;
    }
    if (cur >= 0) {
        float* ap = sacc + (cur - n0) * 256;
        lds_add(ap + lane, r0);
        lds_add(ap + 32 + lane, r1);
        lds_add(ap + 64 + lane * 3 + 0, r2);
        lds_add(ap + 64 + lane * 3 + 1, r3);
        lds_add(ap + 64 + lane * 3 + 2, r4);
        lds_add(ap + 160 + lane * 3 + 0, r5);
        lds_add(ap + 160 + lane * 3 + 1, r6);
        lds_add(ap + 160 + lane * 3 + 2, r7);
    }
    asm volatile("s_waitcnt lgkmcnt(0)" ::: "memory");
    __syncthreads();

    const float scale = 0.31622776601683794f * 0.125f * 0.3872983346207417f;
    for (int li = g; li < NPB; li += GROUPS) {
        const float* ap = sacc + li * 256;
        float cs = 0.f, cv0 = 0.f, cv1 = 0.f, cv2 = 0.f;
#pragma unroll 8
        for (int j = 0; j < 64; ++j) {
            const float as = ap[j];
            cs += as * __ldg(&W2_s[j * 32 + lane]);
            const float wv = __ldg(&W2_v[j * 32 + lane]);
            cv0 += ap[64 + 3 * j + 0] * wv;
            cv1 += ap[64 + 3 * j + 1] * wv;
            cv2 += ap[64 + 3 * j + 2] * wv;
        }
        float* o = out + (size_t)(n0 + li) * 128;
        o[lane]              += scale * cs;
        o[32 + lane * 3 + 0] += scale * cv0;
        o[32 + lane * 3 + 1] += scale * cv1;
        o[32 + lane * 3 + 2] += scale * cv2;
    }
}

extern "C" void kernel_launch(void* const* d_in, const int* in_sizes, int n_in,
                              void* d_out, int out_size, void* d_ws, size_t ws_size,
                              hipStream_t stream) {
    const float* node_input   = (const float*)d_in[0];
    const float* edge_attr    = (const float*)d_in[1];
    const float* edge_scalars = (const float*)d_in[2];
    const float* W1_s = (const float*)d_in[3];
    const float* W1_v = (const float*)d_in[4];
    const float* M0   = (const float*)d_in[5];
    const float* M1   = (const float*)d_in[6];
    const float* Wtp0 = (const float*)d_in[7];
    const float* Wtp1 = (const float*)d_in[8];
    const float* Wtp2 = (const float*)d_in[9];
    const float* Wtp3 = (const float*)d_in[10];
    const float* W2_s = (const float*)d_in[11];
    const float* W2_v = (const float*)d_in[12];
    const int* edge_src = (const int*)d_in[13];
    const int* edge_dst = (const int*)d_in[14];
    float* out = (float*)d_out;
    float* ws  = (float*)d_ws;

    float*  feat    = ws;                                           // N*128 (25.6 MB)
    float4* ySorted = (float4*)(feat + (size_t)N_NODES * 128);      // E float4 (8 MB)
    uint4*  hBuf    = (uint4*)(ySorted + N_EDGES);                  // E*4 uint4 (32 MB)
    int4*   sde     = (int4*)(hBuf + (size_t)N_EDGES * 4);          // E int4 (8 MB)
    int*    counts  = (int*)(sde + N_EDGES);                        // N
    int*    offsets = counts + N_NODES;                             // N+1
    int*    cursor  = offsets + N_NODES + 1;                        // N
    // total ~74 MB

    hipMemsetAsync(counts, 0, N_NODES * sizeof(int), stream);

    node_pre<<<(N_NODES + 255) / 256, 256, 0, stream>>>(node_input, W1_s, W1_v,
                                                        feat, out);

    hist_kernel<<<(N_EDGES + 255) / 256, 256, 0, stream>>>(edge_dst, counts);
    scan_kernel<<<1, 1024, 0, stream>>>(counts, offsets, cursor);
    scatter_kernel<<<(N_EDGES + 255) / 256, 256, 0, stream>>>(edge_src, edge_dst,
                                                              edge_attr,
                                                              cursor, ySorted, sde);

    h_kernel<<<(N_EDGES + 255) / 256, 256, 0, stream>>>(edge_scalars, M0, M1, hBuf);

    conv_kernel<<<N_NODES / NPB, 256, 0, stream>>>(hBuf, ySorted, sde, offsets,
                                                   Wtp0, Wtp1, Wtp2, Wtp3,
                                                   W2_s, W2_v, feat, out);
}